// Round 15
// baseline (666.579 us; speedup 1.0000x reference)
//
#include <hip/hip_runtime.h>
#include <hip/hip_bf16.h>

#define D 128
#define BRF 256    // rows per block for GEMM kernels (196 blocks at N=50000)
#define KC 32      // K-chunk
#define PWT 132    // Ws pitch (float4-aligned; 2-way on reads = free)
#define PXT 260    // XsT pitch (float4-aligned reads; 4-way only on stage writes)

// ---------------------------------------------------------------------------
// CSR build: deg count -> exclusive scan -> fill   (unchanged)
// ---------------------------------------------------------------------------
__global__ void count_deg(const int* __restrict__ ei, int* __restrict__ deg, int E) {
    int e = blockIdx.x * 256 + threadIdx.x;
    if (e < E) atomicAdd(&deg[ei[E + e]], 1);
}

__global__ __launch_bounds__(256) void scan_kernel(const int* __restrict__ deg,
                                                   int* __restrict__ rowstart,
                                                   int* __restrict__ cursor, int n) {
    __shared__ int tsum[257];
    int tid = threadIdx.x;
    int chunk = (n + 255) / 256;
    int lo = tid * chunk;
    int hi = lo + chunk; if (hi > n) hi = n;
    int s = 0;
    for (int i = lo; i < hi; ++i) s += deg[i];
    tsum[tid] = s;
    __syncthreads();
    if (tid == 0) {
        int run = 0;
        for (int i = 0; i < 256; ++i) { int t = tsum[i]; tsum[i] = run; run += t; }
        tsum[256] = run;
    }
    __syncthreads();
    int run = tsum[tid];
    for (int i = lo; i < hi; ++i) {
        rowstart[i] = run; cursor[i] = run; run += deg[i];
    }
    if (tid == 0) rowstart[n] = tsum[256];
}

__global__ void fill_csr(const int* __restrict__ ei, int* __restrict__ cursor,
                         int* __restrict__ csr, int E) {
    int e = blockIdx.x * 256 + threadIdx.x;
    if (e < E) {
        int s = ei[e];
        int d = ei[E + e];
        int p = atomicAdd(&cursor[d], 1);
        csr[p] = s;
    }
}

// ---------------------------------------------------------------------------
// GEMM skeleton: 256-row tile, 256 threads, 16x8 per thread.
// tr=tid>>4 (16 row-groups x 16 rows), tc=tid&15; cols = {4tc..+4} u {64+4tc..+4}
// Per k: xs = 4x b128 broadcast (XsT), ws = 2x b128 2-way (Ws). 128 FMA.
// ---------------------------------------------------------------------------

// m_nodes = x @ W_msg + b_msg   (K = 128)
__global__ __launch_bounds__(256) void gemm128(const float* __restrict__ src,
                                               const float* __restrict__ W,
                                               const float* __restrict__ b,
                                               float* __restrict__ out, int n) {
    __shared__ __align__(16) float Ws[KC * PWT];
    __shared__ __align__(16) float XsT[KC * PXT];
    const int tid = threadIdx.x;
    const int R0 = blockIdx.x * BRF;
    const int tr = tid >> 4, tc = tid & 15;
    const int r0 = tr * 16, c0a = tc * 4, c0b = 64 + tc * 4;

    float acc[16][8];
#pragma unroll
    for (int i = 0; i < 16; ++i)
#pragma unroll
        for (int j = 0; j < 8; ++j) acc[i][j] = 0.f;

    for (int ch = 0; ch < 4; ++ch) {
        const int k0 = ch * KC;
        if (ch) __syncthreads();
#pragma unroll
        for (int t = 0; t < 16; ++t) {          // Ws: 32x128
            int e = t * 256 + tid;
            int k = e >> 7, c = e & 127;
            Ws[k * PWT + c] = W[(k0 + k) * D + c];
        }
#pragma unroll
        for (int t = 0; t < 32; ++t) {          // XsT: 32k x 256r, transposed
            int e = t * 256 + tid;
            int c = e & 31, r = e >> 5;
            int gr = R0 + r; if (gr >= n) gr = n - 1;
            XsT[c * PXT + r] = src[(long)gr * D + k0 + c];
        }
        __syncthreads();
        for (int k = 0; k < KC; ++k) {
            float xs[16];
            *(float4*)&xs[0]  = *(const float4*)&XsT[k * PXT + r0];
            *(float4*)&xs[4]  = *(const float4*)&XsT[k * PXT + r0 + 4];
            *(float4*)&xs[8]  = *(const float4*)&XsT[k * PXT + r0 + 8];
            *(float4*)&xs[12] = *(const float4*)&XsT[k * PXT + r0 + 12];
            float4 wa = *(const float4*)&Ws[k * PWT + c0a];
            float4 wb = *(const float4*)&Ws[k * PWT + c0b];
#pragma unroll
            for (int i = 0; i < 16; ++i) {
                acc[i][0] += xs[i] * wa.x; acc[i][1] += xs[i] * wa.y;
                acc[i][2] += xs[i] * wa.z; acc[i][3] += xs[i] * wa.w;
                acc[i][4] += xs[i] * wb.x; acc[i][5] += xs[i] * wb.y;
                acc[i][6] += xs[i] * wb.z; acc[i][7] += xs[i] * wb.w;
            }
        }
    }

    const float4 ba = *(const float4*)&b[c0a];
    const float4 bb = *(const float4*)&b[c0b];
#pragma unroll
    for (int i = 0; i < 16; ++i) {
        int row = R0 + r0 + i;
        if (row < n) {
            float4 o0, o1;
            o0.x = acc[i][0] + ba.x; o0.y = acc[i][1] + ba.y;
            o0.z = acc[i][2] + ba.z; o0.w = acc[i][3] + ba.w;
            o1.x = acc[i][4] + bb.x; o1.y = acc[i][5] + bb.y;
            o1.z = acc[i][6] + bb.z; o1.w = acc[i][7] + bb.w;
            *(float4*)&out[(long)row * D + c0a] = o0;
            *(float4*)&out[(long)row * D + c0b] = o1;
        }
    }
}

// conv = [x | aggr] @ W_upd + b_upd   (K = 256; chunks 0-3 from x, 4-7 from aggr)
__global__ __launch_bounds__(256) void gemm_upd(const float* __restrict__ x,
                                                const float* __restrict__ aggr,
                                                const float* __restrict__ W,
                                                const float* __restrict__ b,
                                                float* __restrict__ out, int n) {
    __shared__ __align__(16) float Ws[KC * PWT];
    __shared__ __align__(16) float XsT[KC * PXT];
    const int tid = threadIdx.x;
    const int R0 = blockIdx.x * BRF;
    const int tr = tid >> 4, tc = tid & 15;
    const int r0 = tr * 16, c0a = tc * 4, c0b = 64 + tc * 4;

    float acc[16][8];
#pragma unroll
    for (int i = 0; i < 16; ++i)
#pragma unroll
        for (int j = 0; j < 8; ++j) acc[i][j] = 0.f;

    for (int ch = 0; ch < 8; ++ch) {
        const int k0 = ch * KC;                 // W_upd row offset
        const float* src = (ch < 4) ? x : aggr;
        const int koff = (ch & 3) * KC;         // column offset into src
        if (ch) __syncthreads();
#pragma unroll
        for (int t = 0; t < 16; ++t) {
            int e = t * 256 + tid;
            int k = e >> 7, c = e & 127;
            Ws[k * PWT + c] = W[(k0 + k) * D + c];
        }
#pragma unroll
        for (int t = 0; t < 32; ++t) {
            int e = t * 256 + tid;
            int c = e & 31, r = e >> 5;
            int gr = R0 + r; if (gr >= n) gr = n - 1;
            XsT[c * PXT + r] = src[(long)gr * D + koff + c];
        }
        __syncthreads();
        for (int k = 0; k < KC; ++k) {
            float xs[16];
            *(float4*)&xs[0]  = *(const float4*)&XsT[k * PXT + r0];
            *(float4*)&xs[4]  = *(const float4*)&XsT[k * PXT + r0 + 4];
            *(float4*)&xs[8]  = *(const float4*)&XsT[k * PXT + r0 + 8];
            *(float4*)&xs[12] = *(const float4*)&XsT[k * PXT + r0 + 12];
            float4 wa = *(const float4*)&Ws[k * PWT + c0a];
            float4 wb = *(const float4*)&Ws[k * PWT + c0b];
#pragma unroll
            for (int i = 0; i < 16; ++i) {
                acc[i][0] += xs[i] * wa.x; acc[i][1] += xs[i] * wa.y;
                acc[i][2] += xs[i] * wa.z; acc[i][3] += xs[i] * wa.w;
                acc[i][4] += xs[i] * wb.x; acc[i][5] += xs[i] * wb.y;
                acc[i][6] += xs[i] * wb.z; acc[i][7] += xs[i] * wb.w;
            }
        }
    }

    const float4 ba = *(const float4*)&b[c0a];
    const float4 bb = *(const float4*)&b[c0b];
#pragma unroll
    for (int i = 0; i < 16; ++i) {
        int row = R0 + r0 + i;
        if (row < n) {
            float4 o0, o1;
            o0.x = acc[i][0] + ba.x; o0.y = acc[i][1] + ba.y;
            o0.z = acc[i][2] + ba.z; o0.w = acc[i][3] + ba.w;
            o1.x = acc[i][4] + bb.x; o1.y = acc[i][5] + bb.y;
            o1.z = acc[i][6] + bb.z; o1.w = acc[i][7] + bb.w;
            *(float4*)&out[(long)row * D + c0a] = o0;
            *(float4*)&out[(long)row * D + c0b] = o1;
        }
    }
}

// gate = sigmoid(conv@Wg[0:128] + imp*Wg[128] + bg); out = gate*conv+(1-gate)*x;
// p_imp = out @ W_imp + b_imp
__global__ __launch_bounds__(256) void gate_mix(const float* __restrict__ conv,
                                                const float* __restrict__ x,
                                                const float* __restrict__ imp,
                                                const float* __restrict__ Wg,
                                                const float* __restrict__ bg,
                                                const float* __restrict__ Wi,
                                                const float* __restrict__ bi_p,
                                                float* __restrict__ out, int n) {
    __shared__ __align__(16) float Ws[KC * PWT];
    __shared__ __align__(16) float XsT[KC * PXT];
    const int tid = threadIdx.x;
    const int R0 = blockIdx.x * BRF;
    const int tr = tid >> 4, tc = tid & 15;
    const int r0 = tr * 16, c0a = tc * 4, c0b = 64 + tc * 4;

    float acc[16][8];
#pragma unroll
    for (int i = 0; i < 16; ++i)
#pragma unroll
        for (int j = 0; j < 8; ++j) acc[i][j] = 0.f;

    for (int ch = 0; ch < 4; ++ch) {
        const int k0 = ch * KC;
        if (ch) __syncthreads();
#pragma unroll
        for (int t = 0; t < 16; ++t) {
            int e = t * 256 + tid;
            int k = e >> 7, c = e & 127;
            Ws[k * PWT + c] = Wg[(k0 + k) * D + c];
        }
#pragma unroll
        for (int t = 0; t < 32; ++t) {
            int e = t * 256 + tid;
            int c = e & 31, r = e >> 5;
            int gr = R0 + r; if (gr >= n) gr = n - 1;
            XsT[c * PXT + r] = conv[(long)gr * D + k0 + c];
        }
        __syncthreads();
        for (int k = 0; k < KC; ++k) {
            float xs[16];
            *(float4*)&xs[0]  = *(const float4*)&XsT[k * PXT + r0];
            *(float4*)&xs[4]  = *(const float4*)&XsT[k * PXT + r0 + 4];
            *(float4*)&xs[8]  = *(const float4*)&XsT[k * PXT + r0 + 8];
            *(float4*)&xs[12] = *(const float4*)&XsT[k * PXT + r0 + 12];
            float4 wa = *(const float4*)&Ws[k * PWT + c0a];
            float4 wb = *(const float4*)&Ws[k * PWT + c0b];
#pragma unroll
            for (int i = 0; i < 16; ++i) {
                acc[i][0] += xs[i] * wa.x; acc[i][1] += xs[i] * wa.y;
                acc[i][2] += xs[i] * wa.z; acc[i][3] += xs[i] * wa.w;
                acc[i][4] += xs[i] * wb.x; acc[i][5] += xs[i] * wb.y;
                acc[i][6] += xs[i] * wb.z; acc[i][7] += xs[i] * wb.w;
            }
        }
    }

    // epilogue: gate, mix, store, p_imp
    const float4 wga = *(const float4*)&Wg[128 * D + c0a];   // importance row
    const float4 wgb = *(const float4*)&Wg[128 * D + c0b];
    const float4 bga = *(const float4*)&bg[c0a];
    const float4 bgb = *(const float4*)&bg[c0b];
    const float4 wia = *(const float4*)&Wi[c0a];
    const float4 wib = *(const float4*)&Wi[c0b];
    const float bi = bi_p[0];

#pragma unroll
    for (int i = 0; i < 16; ++i) {
        int row = R0 + r0 + i;
        int crow = row < n ? row : n - 1;
        float iv = imp[crow];
        float4 cva = *(const float4*)&conv[(long)crow * D + c0a];
        float4 cvb = *(const float4*)&conv[(long)crow * D + c0b];
        float4 xva = *(const float4*)&x[(long)crow * D + c0a];
        float4 xvb = *(const float4*)&x[(long)crow * D + c0b];

        float z, s;
        z = acc[i][0] + iv * wga.x + bga.x; s = 1.f/(1.f+expf(-z)); acc[i][0] = s*cva.x + (1.f-s)*xva.x;
        z = acc[i][1] + iv * wga.y + bga.y; s = 1.f/(1.f+expf(-z)); acc[i][1] = s*cva.y + (1.f-s)*xva.y;
        z = acc[i][2] + iv * wga.z + bga.z; s = 1.f/(1.f+expf(-z)); acc[i][2] = s*cva.z + (1.f-s)*xva.z;
        z = acc[i][3] + iv * wga.w + bga.w; s = 1.f/(1.f+expf(-z)); acc[i][3] = s*cva.w + (1.f-s)*xva.w;
        z = acc[i][4] + iv * wgb.x + bgb.x; s = 1.f/(1.f+expf(-z)); acc[i][4] = s*cvb.x + (1.f-s)*xvb.x;
        z = acc[i][5] + iv * wgb.y + bgb.y; s = 1.f/(1.f+expf(-z)); acc[i][5] = s*cvb.y + (1.f-s)*xvb.y;
        z = acc[i][6] + iv * wgb.z + bgb.z; s = 1.f/(1.f+expf(-z)); acc[i][6] = s*cvb.z + (1.f-s)*xvb.z;
        z = acc[i][7] + iv * wgb.w + bgb.w; s = 1.f/(1.f+expf(-z)); acc[i][7] = s*cvb.w + (1.f-s)*xvb.w;

        if (row < n) {
            float4 o0, o1;
            o0.x = acc[i][0]; o0.y = acc[i][1]; o0.z = acc[i][2]; o0.w = acc[i][3];
            o1.x = acc[i][4]; o1.y = acc[i][5]; o1.z = acc[i][6]; o1.w = acc[i][7];
            *(float4*)&out[(long)row * D + c0a] = o0;
            *(float4*)&out[(long)row * D + c0b] = o1;
        }

        float pi = acc[i][0]*wia.x + acc[i][1]*wia.y + acc[i][2]*wia.z + acc[i][3]*wia.w
                 + acc[i][4]*wib.x + acc[i][5]*wib.y + acc[i][6]*wib.z + acc[i][7]*wib.w;
#pragma unroll
        for (int m = 8; m >= 1; m >>= 1) pi += __shfl_xor(pi, m, 16);
        if (tc == 0 && row < n) out[(long)n * D + row] = pi + bi;
    }
}

// ---------------------------------------------------------------------------
// aggr[n] = sum over incoming edges of m_nodes[src]; one wave/node, unroll 4.
// ---------------------------------------------------------------------------
__global__ __launch_bounds__(256) void aggr_kernel(const float* __restrict__ mn,
                                                   const int* __restrict__ rowstart,
                                                   const int* __restrict__ csr,
                                                   float* __restrict__ aggr, int n) {
    int gw = (blockIdx.x * 256 + threadIdx.x) >> 6;
    int lane = threadIdx.x & 63;
    if (gw >= n) return;
    int rs = rowstart[gw], re = rowstart[gw + 1];
    float a0x=0.f,a0y=0.f,a1x=0.f,a1y=0.f,a2x=0.f,a2y=0.f,a3x=0.f,a3y=0.f;
    int i = rs;
    for (; i + 3 < re; i += 4) {
        int s0 = csr[i], s1 = csr[i+1], s2 = csr[i+2], s3 = csr[i+3];
        float2 v0 = *(const float2*)&mn[(long)s0 * D + lane * 2];
        float2 v1 = *(const float2*)&mn[(long)s1 * D + lane * 2];
        float2 v2 = *(const float2*)&mn[(long)s2 * D + lane * 2];
        float2 v3 = *(const float2*)&mn[(long)s3 * D + lane * 2];
        a0x += v0.x; a0y += v0.y; a1x += v1.x; a1y += v1.y;
        a2x += v2.x; a2y += v2.y; a3x += v3.x; a3y += v3.y;
    }
    for (; i < re; ++i) {
        int s0 = csr[i];
        float2 v0 = *(const float2*)&mn[(long)s0 * D + lane * 2];
        a0x += v0.x; a0y += v0.y;
    }
    float2 o; o.x = (a0x + a1x) + (a2x + a3x); o.y = (a0y + a1y) + (a2y + a3y);
    *(float2*)&aggr[(long)gw * D + lane * 2] = o;
}

// ---------------------------------------------------------------------------
extern "C" void kernel_launch(void* const* d_in, const int* in_sizes, int n_in,
                              void* d_out, int out_size, void* d_ws, size_t ws_size,
                              hipStream_t stream) {
    const float* x      = (const float*)d_in[0];
    const int*   ei     = (const int*)d_in[1];
    const float* imp    = (const float*)d_in[2];
    const float* W_msg  = (const float*)d_in[3];
    const float* b_msg  = (const float*)d_in[4];
    const float* W_upd  = (const float*)d_in[5];
    const float* b_upd  = (const float*)d_in[6];
    const float* W_gate = (const float*)d_in[7];
    const float* b_gate = (const float*)d_in[8];
    const float* W_imp  = (const float*)d_in[9];
    const float* b_imp  = (const float*)d_in[10];
    float* out = (float*)d_out;

    const int N = in_sizes[0] / D;
    const int E = in_sizes[1] / 2;

    char* ws = (char*)d_ws;
    float* m_nodes  = (float*)ws;  ws += (size_t)N * D * sizeof(float);  // reused as conv
    float* aggr     = (float*)ws;  ws += (size_t)N * D * sizeof(float);
    int*   deg      = (int*)ws;    ws += (size_t)N * sizeof(int);
    int*   rowstart = (int*)ws;    ws += (size_t)(N + 1) * sizeof(int);
    int*   cursor   = (int*)ws;    ws += (size_t)N * sizeof(int);
    int*   csr      = (int*)ws;    ws += (size_t)E * sizeof(int);

    hipMemsetAsync(deg, 0, (size_t)N * sizeof(int), stream);

    count_deg<<<(E + 255) / 256, 256, 0, stream>>>(ei, deg, E);
    scan_kernel<<<1, 256, 0, stream>>>(deg, rowstart, cursor, N);
    fill_csr<<<(E + 255) / 256, 256, 0, stream>>>(ei, cursor, csr, E);

    const int nblk = (N + BRF - 1) / BRF;   // 196 at N=50000
    gemm128<<<nblk, 256, 0, stream>>>(x, W_msg, b_msg, m_nodes, N);

    aggr_kernel<<<((size_t)N * 64 + 255) / 256, 256, 0, stream>>>(
        m_nodes, rowstart, csr, aggr, N);

    // conv reuses the m_nodes buffer (m_nodes dead after aggr)
    float* conv = m_nodes;
    gemm_upd<<<nblk, 256, 0, stream>>>(x, aggr, W_upd, b_upd, conv, N);

    gate_mix<<<nblk, 256, 0, stream>>>(conv, x, imp, W_gate, b_gate,
                                       W_imp, b_imp, out, N);
}